// Round 1
// baseline (162.912 us; speedup 1.0000x reference)
//
#include <hip/hip_runtime.h>
#include <math.h>

#define G    64
#define NPG  2048
#define NTOT (G * NPG)          // 131072
#define EPG  (NPG * 8)          // 16384 edges per graph
#define NE   (NTOT * 8)
#define KSEL 410
#define NH   3
#define NC   20
#define HC   60
#define FCAP 24
#define KPAD 512
#define RP   12                 // x1g padded row: x1[0..9], dinv@10, hs@11 (48 B)

// ---------------- K1 arena (quarter-CSR GCN), bytes ----------------
#define A1_H1P   0              // 98304  h1p 2048x12f
#define A1_HIST  98304          // 8192   full-graph degree hist (int)
#define A1_RSQ   106496         // 2064   rsQ[513] int (quarter CSR offsets)
#define A1_CURQ  108560         // 2048   curQ[512] int cursors
#define A1_CSRQ  110608         // 32768  csrQ u16[16384] (cap = all edges, no overflow)
#define A1_WSUM  143376         // 64
#define A1_SZ    143440

// ---------------- K2 arena (scorer/select/GAT/MLP), bytes ----------
// liveness: P1 stage, P2 scatter, P3 keys, P4 select, P5 pool+fadj, P6 feat, P7 agg, P8 mlp
#define A2_PR    0              // 8192   pr = dinv*hs          [P1..P3]
#define A2_XP    0              // 16400  xp 410x10f            [P5..P6]  (pr/di dead)
#define A2_DI    8192           // 8192   dinv                  [P1..P3]
#define A2_SUM   16384          // 8192   scatter sums          [P1..P3]
#define A2_FADJ  16400          // 19680  fadj 410x24 u16       [P5..P7]  (sum dead)
#define A2_FCNT  36080          // 1648   fcnt int              [P3..P7]
#define A2_SK    37728          // 8192   sortable keys u32     [P3..P5]
#define A2_ALS   37728          // 4920   als                   [P6..P7]  (sk dead)
#define A2_ALD   42648          // 4920   ald                   [P6..P7]
#define A2_HIST  45920          // 8192   radix hist int        [P1..P4]
#define A2_WRED  47568          // 1920   wave partials         [P7]      (hist dead)
#define A2_GOUT  49488          // 240                          [P7..P8]
#define A2_HID   49728          // 120                          [P8]
#define A2_NEWL  54112          // 4096   newL u16              [P1..P5]
#define A2_PERML 58208          // 824    permL u16             [P4..P5]
#define A2_WSUM  59032          // 64
#define A2_FLAGS 59096          // 16
#define A2_HF    59120          // 98400  hf 410x60f            [P6..P7]
#define A2_SZ    157520

__device__ inline float leaky(float x) { return x >= 0.f ? x : 0.2f * x; }

__device__ inline int wave_incl_scan(int v) {
    int lane = threadIdx.x & 63;
#pragma unroll
    for (int d = 1; d < 64; d <<= 1) {
        int t = __shfl_up(v, d, 64);
        if (lane >= d) v += t;
    }
    return v;
}

// ================= K1: GCN(5->10) + scorer pre-dot, 4 blocks/graph =================
__global__ __launch_bounds__(1024) void k1_gcn(
    const float* __restrict__ x, const int* __restrict__ src, const int* __restrict__ dst,
    const float* __restrict__ W1, const float* __restrict__ b1, const float* __restrict__ Ws,
    float* __restrict__ x1g)
{
    __shared__ __align__(16) char arena[A1_SZ];
    float*          h1p   = (float*)(arena + A1_H1P);
    int*            hist  = (int*)(arena + A1_HIST);
    int*            rsQ   = (int*)(arena + A1_RSQ);
    int*            curQ  = (int*)(arena + A1_CURQ);
    unsigned short* csrQ  = (unsigned short*)(arena + A1_CSRQ);
    int*            wsumL = (int*)(arena + A1_WSUM);

    int bx = blockIdx.x, tid = threadIdx.x, wid = tid >> 6;
    // g = bx&63, q = bx>>6: the 4 blocks of a graph land on the SAME XCD (64 % 8 == 0)
    int g = bx & 63, q = bx >> 6;
    int nbase = g * NPG, ebase = g * EPG, qbase = q << 9;

    // zero hist; h1 = x @ W1 for the WHOLE graph (needed as gather source)
    for (int i = tid; i < NPG; i += 1024) hist[i] = 0;
    for (int i = tid; i < NPG; i += 1024) {
        float xi[5];
#pragma unroll
        for (int k = 0; k < 5; k++) xi[k] = x[(size_t)(nbase + i) * 5 + k];
        float v[10];
#pragma unroll
        for (int j = 0; j < 10; j++) {
            float s = 0.f;
#pragma unroll
            for (int k = 0; k < 5; k++) s += xi[k] * W1[k * 10 + j];
            v[j] = s;
        }
        float4* row = (float4*)(h1p + i * RP);
        row[0] = make_float4(v[0], v[1], v[2], v[3]);
        row[1] = make_float4(v[4], v[5], v[6], v[7]);
        row[2] = make_float4(v[8], v[9], 0.f, 0.f);   // slot 10 = dinv (written below)
    }
    __syncthreads();
    // full-graph in-degree (neighbors' dinv is needed in the gather)
    for (int e = tid; e < EPG; e += 1024)
        atomicAdd(&hist[dst[ebase + e] - nbase], 1);
    __syncthreads();
    for (int i = tid; i < NPG; i += 1024)
        h1p[i * RP + 10] = rsqrtf((float)hist[i] + 1.0f);
    // exclusive scan over THIS quarter's 512 degrees (waves 0..7)
    int dvv = 0;
    if (tid < 512) { dvv = hist[qbase + tid]; curQ[tid] = 0; }
    int incl = wave_incl_scan(dvv);
    if (tid < 512 && (tid & 63) == 63) wsumL[wid] = incl;
    __syncthreads();
    if (tid == 0) {
        int a = 0;
#pragma unroll
        for (int w = 0; w < 8; w++) { int t = wsumL[w]; wsumL[w] = a; a += t; }
        rsQ[512] = a;
    }
    __syncthreads();
    if (tid < 512) rsQ[tid] = wsumL[wid] + incl - dvv;
    __syncthreads();
    // quarter-CSR fill (scan all graph edges, keep dst in [qbase, qbase+512))
    for (int e = tid; e < EPG; e += 1024) {
        int ee = ebase + e;
        int dl = dst[ee] - nbase;
        if ((dl >> 9) == q) {
            int j = dl - qbase;
            int pos = rsQ[j] + atomicAdd(&curQ[j], 1);
            csrQ[pos] = (unsigned short)(src[ee] - nbase);
        }
    }
    __syncthreads();
    // gather: 2 threads per node (even/odd edges), combine via shfl_xor
    {
        int p = tid >> 1, half = tid & 1, i = qbase + p;
        float a0 = 0.f, a1 = 0.f, a2 = 0.f, a3 = 0.f, a4 = 0.f;
        float a5 = 0.f, a6 = 0.f, a7 = 0.f, a8 = 0.f, a9 = 0.f;
        int p0 = rsQ[p], p1 = rsQ[p + 1];
        for (int e = p0 + half; e < p1; e += 2) {
            int s = csrQ[e];
            const float4* rw = (const float4*)(h1p + s * RP);
            float4 r0 = rw[0], r1 = rw[1], r2 = rw[2];
            float dv = r2.z;
            a0 += r0.x * dv; a1 += r0.y * dv; a2 += r0.z * dv; a3 += r0.w * dv;
            a4 += r1.x * dv; a5 += r1.y * dv; a6 += r1.z * dv; a7 += r1.w * dv;
            a8 += r2.x * dv; a9 += r2.y * dv;
        }
        a0 += __shfl_xor(a0, 1, 64); a1 += __shfl_xor(a1, 1, 64);
        a2 += __shfl_xor(a2, 1, 64); a3 += __shfl_xor(a3, 1, 64);
        a4 += __shfl_xor(a4, 1, 64); a5 += __shfl_xor(a5, 1, 64);
        a6 += __shfl_xor(a6, 1, 64); a7 += __shfl_xor(a7, 1, 64);
        a8 += __shfl_xor(a8, 1, 64); a9 += __shfl_xor(a9, 1, 64);
        if (half == 0) {
            const float4* rowi = (const float4*)(h1p + i * RP);
            float4 s0 = rowi[0], s1 = rowi[1], s2v = rowi[2];
            float di = s2v.z, d2 = di * di;
            float v[10];
            v[0] = a0 * di + s0.x * d2 + b1[0];
            v[1] = a1 * di + s0.y * d2 + b1[1];
            v[2] = a2 * di + s0.z * d2 + b1[2];
            v[3] = a3 * di + s0.w * d2 + b1[3];
            v[4] = a4 * di + s1.x * d2 + b1[4];
            v[5] = a5 * di + s1.y * d2 + b1[5];
            v[6] = a6 * di + s1.z * d2 + b1[6];
            v[7] = a7 * di + s1.w * d2 + b1[7];
            v[8] = a8 * di + s2v.x * d2 + b1[8];
            v[9] = a9 * di + s2v.y * d2 + b1[9];
            float hs = 0.f;
#pragma unroll
            for (int j = 0; j < 10; j++) hs += v[j] * Ws[j];
            float4* xr = (float4*)(x1g + (size_t)(nbase + i) * RP);
            xr[0] = make_float4(v[0], v[1], v[2], v[3]);
            xr[1] = make_float4(v[4], v[5], v[6], v[7]);
            xr[2] = make_float4(v[8], v[9], di, hs);
        }
    }
}

// ================= K2: scorer(scatter) + top-k + pool + GAT + readout + MLP =================
__global__ __launch_bounds__(1024) void k2_rest(
    const int* __restrict__ src, const int* __restrict__ dst,
    const float* __restrict__ bs, const float* __restrict__ Wg,
    const float* __restrict__ a_srcw, const float* __restrict__ a_dstw,
    const float* __restrict__ bg,
    const float* __restrict__ Wf1, const float* __restrict__ bf1,
    const float* __restrict__ Wf2, const float* __restrict__ bf2,
    const float* __restrict__ x1g, float* __restrict__ out)
{
    __shared__ __align__(16) char arena[A2_SZ];
    float*          prL   = (float*)(arena + A2_PR);
    float*          diL   = (float*)(arena + A2_DI);
    float*          sumL  = (float*)(arena + A2_SUM);
    unsigned*       skL   = (unsigned*)(arena + A2_SK);
    int*            hist  = (int*)(arena + A2_HIST);
    unsigned short* newLs = (unsigned short*)(arena + A2_NEWL);
    unsigned short* permL = (unsigned short*)(arena + A2_PERML);
    int*            wsumL = (int*)(arena + A2_WSUM);
    int*            flags = (int*)(arena + A2_FLAGS);
    float*          xpL   = (float*)(arena + A2_XP);
    unsigned short* fadjL = (unsigned short*)(arena + A2_FADJ);
    int*            fcntL = (int*)(arena + A2_FCNT);
    float*          hfL   = (float*)(arena + A2_HF);
    float*          alsL  = (float*)(arena + A2_ALS);
    float*          aldL  = (float*)(arena + A2_ALD);
    float*          wred  = (float*)(arena + A2_WRED);
    float*          goutL = (float*)(arena + A2_GOUT);
    float*          hidL  = (float*)(arena + A2_HID);
#define bselS  flags[0]
#define bneedS flags[1]
#define curS   flags[2]
#define totS   flags[3]

    int g = blockIdx.x, tid = threadIdx.x, wid = tid >> 6;
    int nbase = g * NPG, ebase = g * EPG;

    // ---- P1: stage (dinv,hs) -> pr/di; zero sum; init newL/hist
    for (int i = tid; i < NPG; i += 1024) {
        float2 dh = *(const float2*)(x1g + (size_t)(nbase + i) * RP + 10);
        diL[i] = dh.x;
        prL[i] = dh.x * dh.y;       // dinv * hs
        sumL[i] = 0.f;
        newLs[i] = 0xFFFFu;
        hist[i] = 0;
    }
    __syncthreads();
    // ---- P2: scorer aggregation by scatter (no CSR): sum[dst] += pr[src]
    for (int e = tid; e < EPG; e += 1024) {
        int ee = ebase + e;
        int sl = src[ee] - nbase;
        int dl = dst[ee] - nbase;
        atomicAdd(&sumL[dl], prL[sl]);
    }
    __syncthreads();
    // ---- P3: score -> sortable key; init select state
    float bsv = bs[0];
    for (int i = tid; i < NPG; i += 1024) {
        // score = di*(S + pr) + bs  (== di*S + hs*di^2 + bs)
        float sc = diL[i] * (sumL[i] + prL[i]) + bsv;
        unsigned u = __float_as_uint(sc);
        skL[i] = (u & 0x80000000u) ? ~u : (u | 0x80000000u);
    }
    if (tid < KSEL) fcntL[tid] = 0;
    if (tid == 0) curS = 0;
    int need = KSEL;
    unsigned prefix = 0;
    __syncthreads();

    // ---- P4: 3-level radix select (11/11/10 bits) — unchanged
    for (int lv = 0; lv < 3; lv++) {
        for (int i = tid; i < NPG; i += 1024) {
            unsigned k = skL[i];
            bool match; unsigned bb;
            if (lv == 0)      { match = true;                  bb = k >> 21; }
            else if (lv == 1) { match = ((k >> 21) == prefix); bb = (k >> 10) & 0x7FFu; }
            else              { match = ((k >> 10) == prefix); bb = k & 0x3FFu; }
            if (match) atomicAdd(&hist[bb], 1);
        }
        __syncthreads();
        int b2 = tid * 2;
        int v0 = hist[b2], v1 = hist[b2 + 1];
        hist[b2] = 0; hist[b2 + 1] = 0;
        int s = v0 + v1;
        int incl = wave_incl_scan(s);
        if ((tid & 63) == 63) wsumL[wid] = incl;
        __syncthreads();
        if (tid == 0) {
            int a = 0;
#pragma unroll
            for (int w = 0; w < 16; w++) { int t = wsumL[w]; wsumL[w] = a; a += t; }
            totS = a;
        }
        __syncthreads();
        int base = wsumL[wid] + incl - s;
        int tot = totS;
        { int Sb = tot - base;        int Sb1 = Sb - v0; if (Sb >= need && Sb1 < need) { bselS = b2;     bneedS = need - Sb1; } }
        { int Sb = tot - (base + v0); int Sb1 = Sb - v1; if (Sb >= need && Sb1 < need) { bselS = b2 + 1; bneedS = need - Sb1; } }
        __syncthreads();
        if (lv == 0)      prefix = (unsigned)bselS;
        else if (lv == 1) prefix = (prefix << 11) | (unsigned)bselS;
        else              prefix = (prefix << 10) | (unsigned)bselS;
        need = bneedS;
        __syncthreads();
    }
    unsigned T = prefix;
    int greaterCnt = KSEL - need;

    for (int i = tid; i < NPG; i += 1024) {
        if (skL[i] > T) {
            int p = atomicAdd(&curS, 1);
            permL[p] = (unsigned short)i;
            newLs[i] = (unsigned short)p;
        }
    }
    {   // ties == T: lowest indices first
        int b2 = tid * 2;
        int lc = 0, loc2[2];
#pragma unroll
        for (int k = 0; k < 2; k++)
            if (skL[b2 + k] == T) loc2[lc++] = b2 + k;
        __syncthreads();
        int incl = wave_incl_scan(lc);
        if ((tid & 63) == 63) wsumL[wid] = incl;
        __syncthreads();
        if (tid == 0) {
            int a = 0;
#pragma unroll
            for (int w = 0; w < 16; w++) { int t = wsumL[w]; wsumL[w] = a; a += t; }
        }
        __syncthreads();
        int rank0 = wsumL[wid] + incl - lc;
        for (int j = 0; j < lc; j++) {
            int rank = rank0 + j;
            if (rank < need) {
                int p = greaterCnt + rank;
                permL[p] = (unsigned short)loc2[j];
                newLs[loc2[j]] = (unsigned short)p;
            }
        }
    }
    __syncthreads();

    // ---- P5: gated pooled features + filtered adjacency via edge scan
    for (int p = tid; p < KSEL; p += 1024) {
        int iL = permL[p];
        unsigned k = skL[iL];
        unsigned u = (k & 0x80000000u) ? (k & 0x7FFFFFFFu) : ~k;
        float tt = tanhf(__uint_as_float(u));
        const float4* xr = (const float4*)(x1g + (size_t)(nbase + iL) * RP);
        float4 q0 = xr[0], q1 = xr[1], q2 = xr[2];
        float* xp = xpL + p * 10;
        xp[0] = q0.x * tt; xp[1] = q0.y * tt; xp[2] = q0.z * tt; xp[3] = q0.w * tt;
        xp[4] = q1.x * tt; xp[5] = q1.y * tt; xp[6] = q1.z * tt; xp[7] = q1.w * tt;
        xp[8] = q2.x * tt; xp[9] = q2.y * tt;
    }
    for (int e = tid; e < EPG; e += 1024) {
        int ee = ebase + e;
        unsigned short s2 = newLs[src[ee] - nbase];
        unsigned short d2 = newLs[dst[ee] - nbase];
        if (s2 != 0xFFFFu && d2 != 0xFFFFu) {
            int c = atomicAdd(&fcntL[d2], 1);
            if (c < FCAP) fadjL[d2 * FCAP + c] = s2;
        }
    }
    __syncthreads();

    // ---- P6: GAT features per (p, head)
    for (int t = tid; t < KSEL * NH; t += 1024) {
        int p = t / NH, hh = t - p * NH;
        float xi[10];
#pragma unroll
        for (int k = 0; k < 10; k++) xi[k] = xpL[p * 10 + k];
        float v[NC];
        float as_ = 0.f, ad_ = 0.f;
#pragma unroll
        for (int c = 0; c < NC; c++) {
            int j = hh * NC + c;
            float vv = 0.f;
#pragma unroll
            for (int k = 0; k < 10; k++) vv += xi[k] * Wg[k * HC + j];
            v[c] = vv;
            as_ += vv * a_srcw[j];
            ad_ += vv * a_dstw[j];
        }
        float4* hr = (float4*)(hfL + p * HC + hh * NC);
#pragma unroll
        for (int qq = 0; qq < 5; qq++)
            hr[qq] = make_float4(v[4 * qq], v[4 * qq + 1], v[4 * qq + 2], v[4 * qq + 3]);
        alsL[p * NH + hh] = as_;
        aldL[p * NH + hh] = ad_;
    }
    __syncthreads();

    // ---- P7: softmax agg over filtered adjacency + butterfly readout
    {
        float res[NC];
#pragma unroll
        for (int rnd = 0; rnd < 2; rnd++) {
            int task = rnd == 0 ? tid : 1024 + tid;
            bool on = rnd == 0 || tid < KPAD;
            int hh = task >> 9, p = task & (KPAD - 1);
            if (on) {
                if (p < KSEL) {
                    float aldp = aldL[p * NH + hh];
                    float lself = leaky(alsL[p * NH + hh] + aldp);
                    float m = lself;
                    int c = fcntL[p]; if (c > FCAP) c = FCAP;
                    const unsigned short* f = fadjL + p * FCAP;
                    for (int e = 0; e < c; e++)
                        m = fmaxf(m, leaky(alsL[f[e] * NH + hh] + aldp));
                    float wself = expf(lself - m), wsum = wself;
                    const float4* hp = (const float4*)(hfL + p * HC + hh * NC);
                    float4 r0 = hp[0], r1 = hp[1], r2 = hp[2], r3 = hp[3], r4 = hp[4];
                    r0.x *= wself; r0.y *= wself; r0.z *= wself; r0.w *= wself;
                    r1.x *= wself; r1.y *= wself; r1.z *= wself; r1.w *= wself;
                    r2.x *= wself; r2.y *= wself; r2.z *= wself; r2.w *= wself;
                    r3.x *= wself; r3.y *= wself; r3.z *= wself; r3.w *= wself;
                    r4.x *= wself; r4.y *= wself; r4.z *= wself; r4.w *= wself;
                    for (int e = 0; e < c; e++) {
                        int s2 = f[e];
                        float w = expf(leaky(alsL[s2 * NH + hh] + aldp) - m);
                        wsum += w;
                        const float4* hq = (const float4*)(hfL + s2 * HC + hh * NC);
                        float4 t0 = hq[0], t1 = hq[1], t2 = hq[2], t3 = hq[3], t4 = hq[4];
                        r0.x += w * t0.x; r0.y += w * t0.y; r0.z += w * t0.z; r0.w += w * t0.w;
                        r1.x += w * t1.x; r1.y += w * t1.y; r1.z += w * t1.z; r1.w += w * t1.w;
                        r2.x += w * t2.x; r2.y += w * t2.y; r2.z += w * t2.z; r2.w += w * t2.w;
                        r3.x += w * t3.x; r3.y += w * t3.y; r3.z += w * t3.z; r3.w += w * t3.w;
                        r4.x += w * t4.x; r4.y += w * t4.y; r4.z += w * t4.z; r4.w += w * t4.w;
                    }
                    float inv = 1.f / wsum;
                    res[0] = r0.x * inv;  res[1] = r0.y * inv;  res[2] = r0.z * inv;  res[3] = r0.w * inv;
                    res[4] = r1.x * inv;  res[5] = r1.y * inv;  res[6] = r1.z * inv;  res[7] = r1.w * inv;
                    res[8] = r2.x * inv;  res[9] = r2.y * inv;  res[10] = r2.z * inv; res[11] = r2.w * inv;
                    res[12] = r3.x * inv; res[13] = r3.y * inv; res[14] = r3.z * inv; res[15] = r3.w * inv;
                    res[16] = r4.x * inv; res[17] = r4.y * inv; res[18] = r4.z * inv; res[19] = r4.w * inv;
                } else {
#pragma unroll
                    for (int cc = 0; cc < NC; cc++) res[cc] = 0.f;
                }
#pragma unroll
                for (int cc = 0; cc < NC; cc++) {
                    float v = res[cc];
#pragma unroll
                    for (int d = 1; d < 64; d <<= 1) v += __shfl_xor(v, d, 64);
                    res[cc] = v;
                }
                if ((tid & 63) == 0) {
                    int slot = rnd == 0 ? hh * 8 + (wid & 7) : 16 + wid;
#pragma unroll
                    for (int cc = 0; cc < NC; cc++) wred[slot * NC + cc] = res[cc];
                }
            }
        }
    }
    __syncthreads();
    if (tid < HC) {
        int hh = tid / NC, c = tid - hh * NC;
        float a = 0.f;
#pragma unroll
        for (int w = 0; w < 8; w++) a += wred[(hh * 8 + w) * NC + c];
        goutL[tid] = a + (float)KSEL * bg[tid];
    }
    __syncthreads();

    // ---- P8: MLP + log_softmax
    if (tid < 30) {
        float s = bf1[tid];
#pragma unroll
        for (int k = 0; k < HC; k++) s += goutL[k] * Wf1[k * 30 + tid];
        hidL[tid] = s > 0.f ? s : 0.f;
    }
    __syncthreads();
    if (tid == 0) {
        float z[3];
#pragma unroll
        for (int j = 0; j < 3; j++) {
            float s = bf2[j];
            for (int k = 0; k < 30; k++) s += hidL[k] * Wf2[k * 3 + j];
            z[j] = s;
        }
        float m = fmaxf(z[0], fmaxf(z[1], z[2]));
        float lse = logf(expf(z[0] - m) + expf(z[1] - m) + expf(z[2] - m)) + m;
#pragma unroll
        for (int j = 0; j < 3; j++) out[g * 3 + j] = z[j] - lse;
    }
}

extern "C" void kernel_launch(void* const* d_in, const int* in_sizes, int n_in,
                              void* d_out, int out_size, void* d_ws, size_t ws_size,
                              hipStream_t stream) {
    const float* x     = (const float*)d_in[0];
    const int*   src   = (const int*)d_in[1];
    const int*   dst   = (const int*)d_in[2];
    const float* W1    = (const float*)d_in[4];
    const float* b1    = (const float*)d_in[5];
    const float* Ws    = (const float*)d_in[6];
    const float* bs    = (const float*)d_in[7];
    const float* Wg    = (const float*)d_in[8];
    const float* a_src = (const float*)d_in[9];
    const float* a_dst = (const float*)d_in[10];
    const float* bg    = (const float*)d_in[11];
    const float* Wf1   = (const float*)d_in[12];
    const float* bf1   = (const float*)d_in[13];
    const float* Wf2   = (const float*)d_in[14];
    const float* bf2   = (const float*)d_in[15];
    float* out = (float*)d_out;

    float* x1g = (float*)d_ws;    // 12 * NTOT floats (padded rows), 6.29 MB

    k1_gcn<<<G * 4, 1024, 0, stream>>>(x, src, dst, W1, b1, Ws, x1g);
    k2_rest<<<G, 1024, 0, stream>>>(src, dst, bs, Wg, a_src, a_dst, bg,
                                    Wf1, bf1, Wf2, bf2, x1g, out);
}